// Round 2
// baseline (8810.793 us; speedup 1.0000x reference)
//
#include <hip/hip_runtime.h>
#include <stdint.h>

#define B_   512
#define T_   512

typedef __attribute__((ext_vector_type(8))) __bf16 bf16x8;
typedef __attribute__((ext_vector_type(4))) float f32x4;
typedef __attribute__((ext_vector_type(8))) unsigned short u16x8;

// Layer geometry:
//   l : S   | C   | NPT | KT | XOFF | RS (LDS row stride, elems)
//   0 : 231 | 232 | 15  | 8  | 1    | 280   (dword stride 140 ≡ 12 mod 32 -> 2-way min aliasing)
//   1 : 153 | 384 | 10  | 12 | 231  | 408   (204 ≡ 12)
//   2 : 128 | 281 | 8   | 9  | 153  | 312   (156 ≡ 28)
// Packed weights (bf16) in d_ws: per layer, 3 matrices (G1=W1*mask, G2=W2*mask, G3=Wa+Wb),
// chunk c = ((m*NPT + nt)*KT + kt)*64 + lane, 8 bf16:
//   elem i = G[nt*16 + (lane&15)][kt*32 + (lane>>4)*8 + i]  (zero outside S x C)
// Layer elem offsets: L0=0, L1=184320, L2=368640.

#define RS0 280
#define RS1 408
#define RS2 312

__device__ __forceinline__ uint16_t f2bf(float f){
  union { float f; uint32_t u; } v; v.f = f;
  uint32_t u = v.u;
  u += 0x7FFFu + ((u >> 16) & 1u);
  return (uint16_t)(u >> 16);
}
__device__ __forceinline__ float bf2f(uint16_t h){
  union { uint32_t u; float f; } v; v.u = ((uint32_t)h) << 16;
  return v.f;
}
__device__ __forceinline__ float sigm_f(float x){
  return __builtin_amdgcn_rcpf(1.0f + __builtin_amdgcn_exp2f(-1.4426950408889634f * x));
}
__device__ __forceinline__ float tanh_f(float x){
  return 2.0f * __builtin_amdgcn_rcpf(1.0f + __builtin_amdgcn_exp2f(-2.8853900817779268f * x)) - 1.0f;
}

__global__ void pack_w(const float* __restrict__ W1, const float* __restrict__ W2,
                       const float* __restrict__ Wa, const float* __restrict__ Wb,
                       const float* __restrict__ Msk, uint16_t* __restrict__ dst,
                       int NPT, int KT, int S, int C)
{
  int c = blockIdx.x * 256 + threadIdx.x;
  int chunks = 3 * NPT * KT * 64;
  if (c >= chunks) return;
  int perN = KT * 64;
  int n3 = c / perN, r = c % perN;
  int kt = r >> 6, lane = r & 63;
  int m = n3 / NPT, nt = n3 % NPT;
  int j = nt * 16 + (lane & 15);
  int kb = kt * 32 + (lane >> 4) * 8;
  u16x8 o;
  #pragma unroll
  for (int i = 0; i < 8; ++i){
    int k = kb + i;
    float v = 0.f;
    if (j < S && k < C){
      size_t idx = (size_t)j * C + k;
      if (m == 0)      v = W1[idx] * Msk[idx];
      else if (m == 1) v = W2[idx] * Msk[idx];
      else             v = Wa[idx] + Wb[idx];
    }
    o[i] = f2bf(v);
  }
  *(u16x8*)(dst + (size_t)c * 8) = o;
}

// One layer of one time step. NO barrier inside: caller barriers after.
// Reads Xc (current buffer), writes h into Xh (next-step own buffer, at XOFF)
// and into Xn (next layer's current buffer, at col 0) or global out for LNUM==2.
template<int LNUM, int S, int NPT, int KT, int XOFF, int RSC, int RSN>
__device__ __forceinline__ void layer_step(
    const uint16_t* __restrict__ Xc, uint16_t* __restrict__ Xh,
    uint16_t* __restrict__ Xn, const uint16_t* __restrict__ Wl,
    const float* bias, float* __restrict__ outp,
    int t, int b0, int wave, int lane, int llo, int lhi)
{
  constexpr int NJ = (NPT + 7) >> 3;

  // A fragments for all of K, loaded once, reused by every tile & matrix.
  bf16x8 a[KT];
  {
    const uint16_t* arow = Xc + llo * RSC + lhi * 8;
    #pragma unroll
    for (int kt = 0; kt < KT; ++kt)
      a[kt] = *(const bf16x8*)(arow + kt * 32);
  }

  #pragma unroll
  for (int ji = 0; ji < NJ; ++ji){
    const int jt = wave + ji * 8;
    if (jt < NPT){                               // wave-uniform branch
      const uint32_t cb = (uint32_t)jt * (KT * 512) + (uint32_t)lane * 8;
      // preload the whole weight tile-set (3 matrices x KT chunks) -> registers
      bf16x8 w0[KT], w1[KT], w2[KT];
      #pragma unroll
      for (int kt = 0; kt < KT; ++kt){
        w0[kt] = *(const bf16x8*)(Wl + cb + kt * 512);
        w1[kt] = *(const bf16x8*)(Wl + (uint32_t)(NPT * KT * 512) + cb + kt * 512);
        w2[kt] = *(const bf16x8*)(Wl + (uint32_t)(2 * NPT * KT * 512) + cb + kt * 512);
      }
      f32x4 ac0 = {0.f,0.f,0.f,0.f}, ac1 = ac0, ac2 = ac0;
      #pragma unroll
      for (int kt = 0; kt < KT; ++kt){
        ac0 = __builtin_amdgcn_mfma_f32_16x16x32_bf16(a[kt], w0[kt], ac0, 0, 0, 0);
        ac1 = __builtin_amdgcn_mfma_f32_16x16x32_bf16(a[kt], w1[kt], ac1, 0, 0, 0);
        ac2 = __builtin_amdgcn_mfma_f32_16x16x32_bf16(a[kt], w2[kt], ac2, 0, 0, 0);
      }
      // epilogue: gates + writes (to OTHER buffers -> no barrier needed first)
      const int j = jt * 16 + llo;
      const bool valid = (j < S);
      const float B1 = bias[ji * 3 + 0];
      const float B2 = bias[ji * 3 + 1];
      const float B3 = bias[ji * 3 + 2];
      #pragma unroll
      for (int r = 0; r < 4; ++r){
        const int row = lhi * 4 + r;
        float ff1 = tanh_f(ac0[r] + B1);
        float ff2 = tanh_f(ac1[r] + B2);
        float tt  = sigm_f(ac2[r] + B3);
        float h = ff1 + tt * (ff2 - ff1);
        if (valid){
          uint16_t hb = f2bf(h);
          Xh[row * RSC + XOFF + j] = hb;
          if constexpr (LNUM < 2)
            Xn[row * RSN + j] = hb;
          else
            outp[((size_t)(b0 + row) * T_ + t) * 128 + j] = h;
        }
      }
    }
  }
}

__global__ __launch_bounds__(512, 2) void cfc_main(
    const float* __restrict__ elapsed, const float* __restrict__ enc,
    const float* __restrict__ b1_0, const float* __restrict__ b2_0,
    const float* __restrict__ ba0,  const float* __restrict__ bb0,
    const float* __restrict__ b1_1, const float* __restrict__ b2_1,
    const float* __restrict__ ba1,  const float* __restrict__ bb1,
    const float* __restrict__ b1_2, const float* __restrict__ b2_2,
    const float* __restrict__ ba2,  const float* __restrict__ bb2,
    const uint16_t* __restrict__ Wp, float* __restrict__ out)
{
  const int tid = threadIdx.x;
  const int wave = tid >> 6, lane = tid & 63;
  const int llo = lane & 15, lhi = lane >> 4;
  const int b0 = blockIdx.x * 16;

  __shared__ uint16_t X0[2 * 16 * RS0];
  __shared__ uint16_t X1[2 * 16 * RS1];
  __shared__ uint16_t X2[2 * 16 * RS2];

  for (int i = tid; i < 2 * 16 * RS0; i += 512) X0[i] = 0;
  for (int i = tid; i < 2 * 16 * RS1; i += 512) X1[i] = 0;
  for (int i = tid; i < 2 * 16 * RS2; i += 512) X2[i] = 0;
  __syncthreads();

  // initial hidden states
  for (int i = tid; i < 16 * 512; i += 512){
    int row = i >> 9, c = i & 511;
    float v = enc[(size_t)(b0 + row) * 512 + c];
    uint16_t hb = f2bf(v);
    if (c < 231)       X0[row * RS0 + 1 + c] = hb;        // h0: cols 1..231
    else if (c < 384)  X1[row * RS1 + c] = hb;            // h1: cols 231..383
    else               X2[row * RS2 + (c - 231)] = hb;    // h2: cols 153..280
  }

  // biases -> registers (per-lane j = jt*16+llo)
  float bias0[6], bias1[6], bias2[3];
  #pragma unroll
  for (int ji = 0; ji < 2; ++ji){
    const int jt = wave + ji * 8;
    const int j = jt * 16 + llo;
    const bool v0 = (jt < 15) && (j < 231);
    bias0[ji * 3 + 0] = v0 ? b1_0[j] : 0.f;
    bias0[ji * 3 + 1] = v0 ? b2_0[j] : 0.f;
    bias0[ji * 3 + 2] = v0 ? (ba0[j] + bb0[j]) : 0.f;
    const bool v1 = (jt < 10) && (j < 153);
    bias1[ji * 3 + 0] = v1 ? b1_1[j] : 0.f;
    bias1[ji * 3 + 1] = v1 ? b2_1[j] : 0.f;
    bias1[ji * 3 + 2] = v1 ? (ba1[j] + bb1[j]) : 0.f;
  }
  {
    const int j = wave * 16 + llo;
    const bool v2 = (j < 128);
    bias2[0] = v2 ? b1_2[j] : 0.f;
    bias2[1] = v2 ? b2_2[j] : 0.f;
    bias2[2] = v2 ? (ba2[j] + bb2[j]) : 0.f;
  }

  // x_0 into X0[buf 0], prefetch x_1
  float xt = 0.f;
  if (tid < 16){
    X0[tid * RS0] = f2bf(elapsed[(size_t)(b0 + tid) * T_]);
    xt = elapsed[(size_t)(b0 + tid) * T_ + 1];
  }
  __syncthreads();

  int cur = 0;
  #pragma unroll 1
  for (int t = 0; t < T_; ++t){
    const int nxt = cur ^ 1;
    uint16_t* X0c = X0 + cur * 16 * RS0; uint16_t* X0n = X0 + nxt * 16 * RS0;
    uint16_t* X1c = X1 + cur * 16 * RS1; uint16_t* X1n = X1 + nxt * 16 * RS1;
    uint16_t* X2c = X2 + cur * 16 * RS2; uint16_t* X2n = X2 + nxt * 16 * RS2;

    layer_step<0, 231, 15,  8,   1, RS0, RS1>(X0c, X0n, X1c, Wp,          bias0, out, t, b0, wave, lane, llo, lhi);
    __syncthreads();
    layer_step<1, 153, 10, 12, 231, RS1, RS2>(X1c, X1n, X2c, Wp + 184320, bias1, out, t, b0, wave, lane, llo, lhi);
    __syncthreads();
    layer_step<2, 128,  8,  9, 153, RS2, RS2>(X2c, X2n, nullptr, Wp + 368640, bias2, out, t, b0, wave, lane, llo, lhi);
    // x_{t+1} into next buffer's input column (read only next step)
    if (tid < 16 && t + 1 < T_){
      X0n[tid * RS0] = f2bf(xt);
      if (t + 2 < T_) xt = elapsed[(size_t)(b0 + tid) * T_ + t + 2];
    }
    __syncthreads();
    cur = nxt;
  }

  // rnn_hidden = concat(h0,h1,h2); after 512 steps cur==0
  const size_t OH = (size_t)B_ * T_ * 128;
  for (int i = tid; i < 16 * 512; i += 512){
    int row = i >> 9, c = i & 511;
    float v;
    if (c < 231)      v = bf2f(X0[row * RS0 + 1 + c]);
    else if (c < 384) v = bf2f(X1[row * RS1 + c]);
    else              v = bf2f(X2[row * RS2 + (c - 231)]);
    out[OH + (size_t)(b0 + row) * 512 + c] = v;
  }
}

extern "C" void kernel_launch(void* const* d_in, const int* in_sizes, int n_in,
                              void* d_out, int out_size, void* d_ws, size_t ws_size,
                              hipStream_t stream)
{
  const float* elapsed = (const float*)d_in[0];
  const float* enc     = (const float*)d_in[1];
  const float* W1_0 = (const float*)d_in[2];  const float* b1_0 = (const float*)d_in[3];
  const float* W2_0 = (const float*)d_in[4];  const float* b2_0 = (const float*)d_in[5];
  const float* Wa0  = (const float*)d_in[6];  const float* ba0  = (const float*)d_in[7];
  const float* Wb0  = (const float*)d_in[8];  const float* bb0  = (const float*)d_in[9];
  const float* M0   = (const float*)d_in[10];
  const float* W1_1 = (const float*)d_in[11]; const float* b1_1 = (const float*)d_in[12];
  const float* W2_1 = (const float*)d_in[13]; const float* b2_1 = (const float*)d_in[14];
  const float* Wa1  = (const float*)d_in[15]; const float* ba1  = (const float*)d_in[16];
  const float* Wb1  = (const float*)d_in[17]; const float* bb1  = (const float*)d_in[18];
  const float* M1   = (const float*)d_in[19];
  const float* W1_2 = (const float*)d_in[20]; const float* b1_2 = (const float*)d_in[21];
  const float* W2_2 = (const float*)d_in[22]; const float* b2_2 = (const float*)d_in[23];
  const float* Wa2  = (const float*)d_in[24]; const float* ba2  = (const float*)d_in[25];
  const float* Wb2  = (const float*)d_in[26]; const float* bb2  = (const float*)d_in[27];
  const float* M2   = (const float*)d_in[28];

  uint16_t* wp = (uint16_t*)d_ws;

  pack_w<<<90, 256, 0, stream>>>(W1_0, W2_0, Wa0, Wb0, M0, wp,          15,  8, 231, 232);
  pack_w<<<90, 256, 0, stream>>>(W1_1, W2_1, Wa1, Wb1, M1, wp + 184320, 10, 12, 153, 384);
  pack_w<<<54, 256, 0, stream>>>(W1_2, W2_2, Wa2, Wb2, M2, wp + 368640,  8,  9, 128, 281);

  cfc_main<<<32, 512, 0, stream>>>(elapsed, enc,
                                   b1_0, b2_0, ba0, bb0,
                                   b1_1, b2_1, ba1, bb1,
                                   b1_2, b2_2, ba2, bb2,
                                   wp, (float*)d_out);
}